// Round 14
// baseline (239.138 us; speedup 1.0000x reference)
//
#include <hip/hip_runtime.h>
#include <hip/hip_bf16.h>
#include <stdint.h>

typedef __bf16 bf16_t;
typedef __attribute__((ext_vector_type(8))) __bf16 bf16x8;
typedef __attribute__((ext_vector_type(4))) __bf16 bf16x4;
typedef __attribute__((ext_vector_type(4))) float f32x4;

#define S_LEN 4096
#define DMODEL 1024
#define NHEADS 16
#define DKH 64

// Hardware 2^x (v_exp_f32). Fallback is numerically identical (e^(x ln2)).
#if defined(__has_builtin)
#if __has_builtin(__builtin_amdgcn_exp2f)
#define EXP2F(x) __builtin_amdgcn_exp2f(x)
#endif
#endif
#ifndef EXP2F
#define EXP2F(x) __expf((x)*0.6931471805599453f)
#endif

__device__ __forceinline__ f32x4 mfma16(bf16x8 a, bf16x8 b, f32x4 c) {
  return __builtin_amdgcn_mfma_f32_16x16x32_bf16(a, b, c, 0, 0, 0);
}

// Load 8 consecutive elements at g (fp32 or bf16) as bf16x8.
template <typename TS>
__device__ __forceinline__ bf16x8 load8_bf16(const TS* g) {
  bf16x8 o;
  if constexpr (sizeof(TS) == 4) {
    const float4 f0 = *(const float4*)(g);
    const float4 f1 = *(const float4*)(g + 4);
    o[0] = (bf16_t)f0.x; o[1] = (bf16_t)f0.y; o[2] = (bf16_t)f0.z; o[3] = (bf16_t)f0.w;
    o[4] = (bf16_t)f1.x; o[5] = (bf16_t)f1.y; o[6] = (bf16_t)f1.z; o[7] = (bf16_t)f1.w;
  } else {
    o = *(const bf16x8*)(g);
  }
  return o;
}

// Sync staging: LDS[row][c] holds global chunk c^(row&7) (chunk = 8 elem = 16 B).
// Lane j loads global chunk j (coalesced) and writes physical chunk j^(row&7).
template <typename TS>
__device__ __forceinline__ void stage_tile64(const TS* __restrict__ g, int gstride,
                                             bf16_t* lds, int rows, int tid) {
  for (int i = tid; i < rows * 8; i += 256) {
    const int row = i >> 3, j = i & 7;
    const int c = j ^ (row & 7);
    bf16x8 v = load8_bf16(g + (size_t)row * gstride + j * 8);
    *(bf16x8*)((char*)lds + row * 128 + c * 16) = v;
  }
}

__device__ __forceinline__ bf16x8 frag64(const bf16_t* lds, int row, int g) {
  return *(const bf16x8*)((const char*)lds + row * 128 + ((g ^ (row & 7)) * 16));
}

// async 16B global->LDS DMA (dest = wave-uniform base + lane*16)
__device__ __forceinline__ void gload16(const bf16_t* g, bf16_t* lds) {
  __builtin_amdgcn_global_load_lds(
      (const __attribute__((address_space(1))) unsigned int*)g,
      (__attribute__((address_space(3))) unsigned int*)lds, 16, 0, 0);
}

// ---------------- elementwise fp32 -> bf16 (fallback path only) ----------------
__global__ __launch_bounds__(256) void convert_bf16(const float* __restrict__ src,
                                                    bf16_t* __restrict__ dst) {
  const size_t i = (size_t)(blockIdx.x * 256 + threadIdx.x) * 8;
  bf16x8 v = load8_bf16(src + i);
  *(bf16x8*)(dst + i) = v;
}

// ---------------- merged head: weight transposes (+ optional q conversion) ----------------
__global__ __launch_bounds__(256) void prep_weights(const float* __restrict__ Wq,
                                                    const float* __restrict__ Wo,
                                                    const float* __restrict__ Wk,
                                                    const float* __restrict__ Wv,
                                                    const float* __restrict__ qsrc,
                                                    bf16_t* __restrict__ Wqt,
                                                    bf16_t* __restrict__ Wot,
                                                    bf16_t* __restrict__ Wkt,
                                                    bf16_t* __restrict__ Wvt,
                                                    bf16_t* __restrict__ qdst) {
  const int b = blockIdx.x;
  const int tid = threadIdx.x;
  if (b >= 544) {  // q conversion chunk
    const size_t i = ((size_t)(b - 544) * 256 + tid) * 8;
    bf16x8 v = load8_bf16(qsrc + i);
    *(bf16x8*)(qdst + i) = v;
    return;
  }
  const float* src; bf16_t* dst; int ss, ds_, bx, by;
  if (b < 256)      { src = Wq; dst = Wqt; ss = 1024; ds_ = 1024; bx = b & 15;         by = b >> 4; }
  else if (b < 512) { src = Wo; dst = Wot; ss = 1024; ds_ = 1024; bx = (b - 256) & 15; by = (b - 256) >> 4; }
  else if (b < 528) { src = Wk; dst = Wkt; ss = 64;   ds_ = 1024; bx = 0;              by = b - 512; }
  else              { src = Wv; dst = Wvt; ss = 64;   ds_ = 1024; bx = 0;              by = b - 528; }

  __shared__ bf16_t t[64][65];
  const int r0 = by * 64, c0 = bx * 64;
#pragma unroll
  for (int it = 0; it < 2; ++it) {
    int idx = tid + it * 256;
    int r = idx >> 3, c8 = idx & 7;
    bf16x8 v = load8_bf16(src + (size_t)(r0 + r) * ss + c0 + c8 * 8);
#pragma unroll
    for (int j = 0; j < 8; ++j) t[c8 * 8 + j][r] = v[j];
  }
  __syncthreads();
#pragma unroll
  for (int it = 0; it < 2; ++it) {
    int idx = tid + it * 256;
    int r = idx >> 3, c8 = idx & 7;
    bf16x8 v;
#pragma unroll
    for (int j = 0; j < 8; ++j) v[j] = t[r][c8 * 8 + j];
    *(bf16x8*)(dst + (size_t)(c0 + r) * ds_ + r0 + c8 * 8) = v;
  }
}

// ---------------- DMA NT GEMM device body (shared by standalone + fused kernels) ----------------
template <typename TC>
__device__ __forceinline__ void gemm_body_dma(char* smem,
                                              const bf16_t* __restrict__ A, int lda,
                                              const bf16_t* __restrict__ Bt, int ldb,
                                              const float* __restrict__ bias,
                                              TC* __restrict__ C, int ldc, int K,
                                              float escale, int m0, int n0) {
  constexpr int BM = 128, BN = 64;
  bf16_t* As = (bf16_t*)smem;            // 2 x 16 KB
  bf16_t* Bs = (bf16_t*)(smem + 32768);  // 2 x 8 KB
  const int tid = threadIdx.x, l = tid & 63, w = tid >> 6;
  const int lr = l & 15, quad = l >> 4;
  const int wm = w * 32;

  const int srow = l >> 3;
  const int sch = (l & 7) ^ srow;
  const bf16_t* a0 = A + (size_t)(m0 + w * 32 + srow) * lda + sch * 8;  // 4 sub-blocks of 8 rows
  const bf16_t* b0 = Bt + (size_t)(n0 + w * 16 + srow) * ldb + sch * 8; // 2 sub-blocks of 8 rows

  f32x4 zero = {0.f, 0.f, 0.f, 0.f};
  f32x4 acc[2][4];
#pragma unroll
  for (int i = 0; i < 2; ++i)
#pragma unroll
    for (int j = 0; j < 4; ++j) acc[i][j] = zero;

  const int nt = K >> 6;

#pragma unroll
  for (int sub = 0; sub < 4; ++sub)
    gload16(a0 + (size_t)sub * 8 * lda, &As[(w * 32 + sub * 8) * 64]);
#pragma unroll
  for (int sub = 0; sub < 2; ++sub)
    gload16(b0 + (size_t)sub * 8 * ldb, &Bs[(w * 16 + sub * 8) * 64]);
  asm volatile("s_waitcnt vmcnt(0)" ::: "memory");
  __builtin_amdgcn_s_barrier();
  asm volatile("" ::: "memory");

  for (int t = 0; t < nt; ++t) {
    const int cur = t & 1;
    if (t + 1 < nt) {
#pragma unroll
      for (int sub = 0; sub < 4; ++sub)
        gload16(a0 + (size_t)(t + 1) * 64 + (size_t)sub * 8 * lda,
                &As[(cur ^ 1) * BM * 64 + (w * 32 + sub * 8) * 64]);
#pragma unroll
      for (int sub = 0; sub < 2; ++sub)
        gload16(b0 + (size_t)(t + 1) * 64 + (size_t)sub * 8 * ldb,
                &Bs[(cur ^ 1) * BN * 64 + (w * 16 + sub * 8) * 64]);
    }
    const bf16_t* Ac = &As[cur * BM * 64];
    const bf16_t* Bc = &Bs[cur * BN * 64];
#pragma unroll
    for (int kc = 0; kc < 2; ++kc) {
      bf16x8 af[2], bfr[4];
#pragma unroll
      for (int rt = 0; rt < 2; ++rt) af[rt] = frag64(Ac, wm + rt * 16 + lr, kc * 4 + quad);
#pragma unroll
      for (int ct = 0; ct < 4; ++ct) bfr[ct] = frag64(Bc, ct * 16 + lr, kc * 4 + quad);
#pragma unroll
      for (int rt = 0; rt < 2; ++rt)
#pragma unroll
        for (int ct = 0; ct < 4; ++ct) acc[rt][ct] = mfma16(af[rt], bfr[ct], acc[rt][ct]);
    }
    asm volatile("s_waitcnt vmcnt(0) lgkmcnt(0)" ::: "memory");
    __builtin_amdgcn_s_barrier();
    asm volatile("" ::: "memory");
  }

#pragma unroll
  for (int rt = 0; rt < 2; ++rt)
#pragma unroll
    for (int ct = 0; ct < 4; ++ct) {
      const int n = n0 + ct * 16 + lr;
      const float bv = bias[n];
      const int mb = m0 + wm + rt * 16 + quad * 4;
#pragma unroll
      for (int r = 0; r < 4; ++r)
        C[(size_t)(mb + r) * ldc + n] = (TC)((acc[rt][ct][r] + bv) * escale);
    }
}

template <typename TC>
__global__ __launch_bounds__(256) void gemm_nt_dma(const bf16_t* __restrict__ A, int lda,
                                                   const bf16_t* __restrict__ Bt, int ldb,
                                                   const float* __restrict__ bias,
                                                   TC* __restrict__ C, int ldc, int K,
                                                   float escale) {
  __shared__ __align__(16) char smem[49152];
  gemm_body_dma<TC>(smem, A, lda, Bt, ldb, bias, C, ldc, K, escale,
                    blockIdx.y * 128, blockIdx.x * 64);
}

// ---------------- K+V split-K projection body (fallback path) ----------------
template <int KSPLIT>
__device__ __forceinline__ void projkv_body(char* smem,
                                            const float* __restrict__ A,
                                            const bf16_t* __restrict__ Bt,
                                            float* __restrict__ part,
                                            int kp, int m0) {
  bf16_t* As = (bf16_t*)smem;            // 16 KB
  bf16_t* Bs = (bf16_t*)(smem + 16384);  // 8 KB
  const int tid = threadIdx.x, l = tid & 63, w = tid >> 6;
  const int lr = l & 15, quad = l >> 4;
  const int kBase = kp * (DMODEL / KSPLIT);
  const int wm = w * 32;

  f32x4 zero = {0.f, 0.f, 0.f, 0.f};
  f32x4 acc[2][4];
#pragma unroll
  for (int i = 0; i < 2; ++i)
#pragma unroll
    for (int j = 0; j < 4; ++j) acc[i][j] = zero;

  for (int t = 0; t < (DMODEL / KSPLIT) / 64; ++t) {
    __syncthreads();
    stage_tile64(A + (size_t)m0 * DMODEL + kBase + t * 64, DMODEL, As, 128, tid);
    stage_tile64(Bt + kBase + t * 64, DMODEL, Bs, 64, tid);
    __syncthreads();
#pragma unroll
    for (int kc = 0; kc < 2; ++kc) {
      bf16x8 af[2], bfr[4];
#pragma unroll
      for (int rt = 0; rt < 2; ++rt) af[rt] = frag64(As, wm + rt * 16 + lr, kc * 4 + quad);
#pragma unroll
      for (int ct = 0; ct < 4; ++ct) bfr[ct] = frag64(Bs, ct * 16 + lr, kc * 4 + quad);
#pragma unroll
      for (int rt = 0; rt < 2; ++rt)
#pragma unroll
        for (int ct = 0; ct < 4; ++ct) acc[rt][ct] = mfma16(af[rt], bfr[ct], acc[rt][ct]);
    }
  }
#pragma unroll
  for (int rt = 0; rt < 2; ++rt)
#pragma unroll
    for (int ct = 0; ct < 4; ++ct) {
      const int n = ct * 16 + lr;
      const int mb = m0 + wm + rt * 16 + quad * 4;
#pragma unroll
      for (int r = 0; r < 4; ++r)
        part[(size_t)kp * S_LEN * 64 + (size_t)(mb + r) * 64 + n] = acc[rt][ct][r];
    }
}

template <int KSPLIT>
__global__ __launch_bounds__(256) void gemm_projkv_partial(const float* __restrict__ Ak,
                                                           const float* __restrict__ Av,
                                                           const bf16_t* __restrict__ Wkt,
                                                           const bf16_t* __restrict__ Wvt,
                                                           float* __restrict__ Pk,
                                                           float* __restrict__ Pv) {
  __shared__ __align__(16) char smem[24576];
  projkv_body<KSPLIT>(smem, blockIdx.z ? Av : Ak, blockIdx.z ? Wvt : Wkt,
                      blockIdx.z ? Pv : Pk, blockIdx.x, blockIdx.y * 128);
}

// ---------------- KSPLIT=1 / BM=64 K or V projection writing kvb (+vtb) directly ----------
// Full K-reduction in-register (16 iters), bias added, bf16 output. V blocks
// additionally LDS-transpose their [64 s][64 d] tile and emit coalesced vtb
// (bf16x8 segments) -- removes the Pk/Pv partial round-trip and reduce_kv.
__device__ __forceinline__ void projkv_direct64(char* smem,
                                                const float* __restrict__ A,
                                                const bf16_t* __restrict__ Bt,
                                                const float* __restrict__ bias,
                                                bf16_t* __restrict__ kvb, int koff,
                                                bf16_t* __restrict__ vtb,  // null for K
                                                int m0) {
  bf16_t* As = (bf16_t*)smem;            // 8 KB
  bf16_t* Bs = (bf16_t*)(smem + 8192);   // 8 KB
  const int tid = threadIdx.x, l = tid & 63, w = tid >> 6;
  const int lr = l & 15, quad = l >> 4;
  const int wm = w * 16;

  f32x4 zero = {0.f, 0.f, 0.f, 0.f};
  f32x4 acc[4];
#pragma unroll
  for (int j = 0; j < 4; ++j) acc[j] = zero;

  for (int t = 0; t < 16; ++t) {
    __syncthreads();
    stage_tile64(A + (size_t)m0 * DMODEL + t * 64, DMODEL, As, 64, tid);
    stage_tile64(Bt + t * 64, DMODEL, Bs, 64, tid);
    __syncthreads();
#pragma unroll
    for (int kc = 0; kc < 2; ++kc) {
      const bf16x8 af = frag64(As, wm + lr, kc * 4 + quad);
      bf16x8 bfr[4];
#pragma unroll
      for (int ct = 0; ct < 4; ++ct) bfr[ct] = frag64(Bs, ct * 16 + lr, kc * 4 + quad);
#pragma unroll
      for (int ct = 0; ct < 4; ++ct) acc[ct] = mfma16(af, bfr[ct], acc[ct]);
    }
  }
  __syncthreads();  // all frag reads done before smem reuse
  bf16_t* tbuf = (bf16_t*)smem;  // [64][68] = 8.5 KB (V path)
#pragma unroll
  for (int ct = 0; ct < 4; ++ct) {
    const int n = ct * 16 + lr;
    const float bv = bias[n];
    const int sl = wm + quad * 4;  // local s 0..63
#pragma unroll
    for (int r = 0; r < 4; ++r) {
      const bf16_t bval = (bf16_t)(acc[ct][r] + bv);
      kvb[(size_t)(m0 + sl + r) * 128 + koff + n] = bval;
      if (vtb) tbuf[(sl + r) * 68 + n] = bval;
    }
  }
  if (vtb) {
    __syncthreads();
    const int dl = tid >> 2;   // 0..63 (d)
    const int s8 = tid & 3;
#pragma unroll
    for (int c = 0; c < 2; ++c) {
      const int chunk = c * 4 + s8;  // 0..7, 8 s-values each
      bf16x8 vv;
#pragma unroll
      for (int j = 0; j < 8; ++j) vv[j] = tbuf[(chunk * 8 + j) * 68 + dl];
      *(bf16x8*)(vtb + (size_t)dl * S_LEN + m0 + chunk * 8) = vv;
    }
  }
}

// ---------------- fused mid dispatch: K/V-proj direct (128 blocks) + Q-proj (512) ----------
__global__ __launch_bounds__(256) void mid_gemms(const bf16_t* __restrict__ qb,
                                                 const bf16_t* __restrict__ Wqt,
                                                 const float* __restrict__ bq,
                                                 bf16_t* __restrict__ qp,
                                                 const float* __restrict__ k,
                                                 const float* __restrict__ v,
                                                 const bf16_t* __restrict__ Wkt,
                                                 const bf16_t* __restrict__ Wvt,
                                                 const float* __restrict__ bk,
                                                 const float* __restrict__ bv,
                                                 bf16_t* __restrict__ kvb,
                                                 bf16_t* __restrict__ vtb,
                                                 float escale) {
  __shared__ __align__(16) char smem[49152];
  const int flat = blockIdx.x;
  if (flat < 128) {  // projkv first: heavier blocks start earliest
    const int z = flat >> 6;           // 0 = K, 1 = V
    const int m0 = (flat & 63) * 64;
    projkv_direct64(smem, z ? v : k, z ? Wvt : Wkt, z ? bv : bk,
                    kvb, z ? 64 : 0, z ? vtb : nullptr, m0);
  } else {
    const int j = flat - 128;          // 0..511
    gemm_body_dma<bf16_t>(smem, qb, 1024, Wqt, 1024, bq, qp, 1024, 1024, escale,
                          (j >> 4) * 128, (j & 15) * 64);
  }
}

// ---------------- reduce split-K partials (fallback path) ----------------
template <int KSPLIT>
__global__ __launch_bounds__(512) void reduce_kv(const float* __restrict__ Pk,
                                                 const float* __restrict__ Pv,
                                                 const float* __restrict__ bk,
                                                 const float* __restrict__ bv,
                                                 bf16_t* __restrict__ kvb,
                                                 bf16_t* __restrict__ vtb) {
  __shared__ bf16_t t[32][65];
  const int tid = threadIdx.x;
  const int s0 = blockIdx.x * 32;
  const int d = tid & 63;
  const int sgrp = tid >> 6;  // 0..7
  const float bkd = bk[d], bvd = bv[d];
#pragma unroll
  for (int i = 0; i < 4; ++i) {
    const int s_local = sgrp * 4 + i;  // 0..31
    const int gid = (s0 + s_local) * 64 + d;
    float sk = bkd, sv = bvd;
#pragma unroll
    for (int p = 0; p < KSPLIT; ++p) {
      sk += Pk[(size_t)p * S_LEN * 64 + gid];
      sv += Pv[(size_t)p * S_LEN * 64 + gid];
    }
    kvb[(size_t)(s0 + s_local) * 128 + d] = (bf16_t)sk;
    kvb[(size_t)(s0 + s_local) * 128 + 64 + d] = (bf16_t)sv;
    t[s_local][d] = (bf16_t)sv;
  }
  __syncthreads();
  if (tid < 256) {
    const int dl = tid >> 2;   // 0..63
    const int s8 = tid & 3;    // chunk of 8 s
    bf16x8 v;
#pragma unroll
    for (int j = 0; j < 8; ++j) v[j] = t[s8 * 8 + j][dl];
    *(bf16x8*)(vtb + (size_t)dl * S_LEN + s0 + s8 * 8) = v;
  }
}

// ---------------- fused flash-style MQA attention v12 (verified best) ----------------
__global__ __launch_bounds__(512, 4) void mqa_attn(const bf16_t* __restrict__ qp,
                                                   const bf16_t* __restrict__ kvb,
                                                   const bf16_t* __restrict__ vtb,
                                                   bf16_t* __restrict__ outp) {
  __shared__ __align__(16) char smem[49152];        // 48 KB
  bf16_t* Ks = (bf16_t*)smem;                       // [2][4096] bf16, 16 KB
  bf16_t* Vs = (bf16_t*)(smem + 16384);             // [2][4096] bf16, 16 KB
  char*   Ps = smem + 32768;                        // 8 waves x 2 KB

  const int tid = threadIdx.x, l = tid & 63, w = tid >> 6;
  const int lr = l & 15, quad = l >> 4;
  const int wq = w >> 1, wk = w & 1;
  const int h = blockIdx.y;
  const int q0 = blockIdx.x * 128;
  const int qrA = q0 + wq * 32 + lr;  // q-tile 0 rows
  const int qrB = qrA + 16;           // q-tile 1 rows
  char* Pw = Ps + w * 2048;           // wave-private [16 rows][128 B]

  const int srow = w * 8 + (l >> 3);
  const int schunk = (l & 7) ^ (srow & 7);
  const bf16_t* ksrc = kvb + (size_t)srow * 128 + schunk * 8;    // +8192 elems/tile
  const bf16_t* vsrc = vtb + (size_t)srow * S_LEN + schunk * 8;  // +64 elems/tile

  const bf16_t* qbA = qp + (size_t)qrA * DMODEL + h * DKH;
  const bf16x8 qfA0 = *(const bf16x8*)(qbA + quad * 8);
  const bf16x8 qfA1 = *(const bf16x8*)(qbA + 32 + quad * 8);
  const bf16_t* qbB = qp + (size_t)qrB * DMODEL + h * DKH;
  const bf16x8 qfB0 = *(const bf16x8*)(qbB + quad * 8);
  const bf16x8 qfB1 = *(const bf16x8*)(qbB + 32 + quad * 8);

  f32x4 zero = {0.f, 0.f, 0.f, 0.f};
  f32x4 o[4][2];  // [d-tile][q-tile], partial over this wave's keys
#pragma unroll
  for (int dt = 0; dt < 4; ++dt) { o[dt][0] = zero; o[dt][1] = zero; }
  float liA = 0.f, liB = 0.f;

  gload16(ksrc, Ks + w * 512);
  gload16(vsrc, Vs + w * 512);
  asm volatile("s_waitcnt vmcnt(0)" ::: "memory");
  __builtin_amdgcn_s_barrier();
  asm volatile("" ::: "memory");

  for (int t = 0; t < S_LEN / 64; ++t) {
    const int cur = t & 1;
    if (t + 1 < S_LEN / 64) {
      gload16(ksrc + (size_t)(t + 1) * 8192, Ks + (cur ^ 1) * 4096 + w * 512);
      gload16(vsrc + (size_t)(t + 1) * 64, Vs + (cur ^ 1) * 4096 + w * 512);
    }
    const bf16_t* Kc = Ks + cur * 4096;
    const bf16_t* Vc = Vs + cur * 4096;

    // ---- S^T = K·Q^T on this wave's 32-key half, both q-tiles ----
    f32x4 st[2][2];  // [kt][qt]
#pragma unroll
    for (int kt = 0; kt < 2; ++kt) {
      const int krow = wk * 32 + kt * 16 + lr;
      const bf16x8 kf0 = frag64(Kc, krow, quad);
      const bf16x8 kf1 = frag64(Kc, krow, 4 + quad);
      f32x4 a0 = mfma16(kf0, qfA0, zero);
      a0 = mfma16(kf1, qfA1, a0);
      st[kt][0] = a0;
      f32x4 a1 = mfma16(kf0, qfB0, zero);
      a1 = mfma16(kf1, qfB1, a1);
      st[kt][1] = a1;
    }

    // ---- p = 2^(s') (Q pre-scaled by log2e); li; pack P (128-B rows) ----
#pragma unroll
    for (int kt = 0; kt < 2; ++kt)
#pragma unroll
      for (int qt = 0; qt < 2; ++qt) {
        bf16x4 pk;
        float rs = 0.f;
#pragma unroll
        for (int r = 0; r < 4; ++r) {
          const float p = EXP2F(st[kt][qt][r]);
          rs += p;
          pk[r] = (bf16_t)p;
        }
        if (qt == 0) liA += rs; else liB += rs;
        *(bf16x4*)(Pw + lr * 128 +
                   ((((qt << 2) + (kt << 1) + (quad >> 1)) ^ (lr & 7)) << 4) +
                   ((quad & 1) << 3)) = pk;
      }
    asm volatile("s_waitcnt lgkmcnt(0)" ::: "memory");  // wave-local drain; no barrier

    // ---- O^T += V^T·P^T on this wave's keys: vf read once, both q-tiles ----
    const bf16x8 pf0 = *(const bf16x8*)(Pw + lr * 128 + ((quad ^ (lr & 7)) << 4));
    const bf16x8 pf1 = *(const bf16x8*)(Pw + lr * 128 + (((4 + quad) ^ (lr & 7)) << 4));
#pragma unroll
    for (int dt = 0; dt < 4; ++dt) {
      const bf16x8 vf = frag64(Vc, dt * 16 + lr, wk * 4 + quad);
      o[dt][0] = mfma16(vf, pf0, o[dt][0]);
      o[dt][1] = mfma16(vf, pf1, o[dt][1]);
    }

    asm volatile("s_waitcnt vmcnt(0) lgkmcnt(0)" ::: "memory");
    __builtin_amdgcn_s_barrier();
    asm volatile("" ::: "memory");
  }

  // ---- epilogue: reduce li over quads in-wave, then pair-sum (wk) via LDS ----
  liA += __shfl_xor(liA, 16, 64);
  liA += __shfl_xor(liA, 32, 64);
  liB += __shfl_xor(liB, 16, 64);
  liB += __shfl_xor(liB, 32, 64);

  float* liBuf = (float*)Ps;  // Ps dead (own-wave pf reads done pre-barrier)
  if (quad == 0) {
    liBuf[w * 32 + lr] = liA;
    liBuf[w * 32 + 16 + lr] = liB;
  }
  float* Obuf = (float*)smem;  // 32 KB: [wq][32 q][64 d]
  if (wk == 1) {
#pragma unroll
    for (int dt = 0; dt < 4; ++dt)
#pragma unroll
      for (int qt = 0; qt < 2; ++qt)
        *(f32x4*)(&Obuf[wq * 2048 + (qt * 16 + lr) * 64 + dt * 16 + quad * 4]) = o[dt][qt];
  }
  __syncthreads();
  if (wk == 0) {
    const float ltA = liA + liBuf[(w ^ 1) * 32 + lr];
    const float ltB = liB + liBuf[(w ^ 1) * 32 + 16 + lr];
    const float invA = 1.f / ltA;
    const float invB = 1.f / ltB;
#pragma unroll
    for (int dt = 0; dt < 4; ++dt) {
      const f32x4 pA = *(const f32x4*)(&Obuf[wq * 2048 + lr * 64 + dt * 16 + quad * 4]);
      const f32x4 pB = *(const f32x4*)(&Obuf[wq * 2048 + (16 + lr) * 64 + dt * 16 + quad * 4]);
      bf16x4 ovA, ovB;
#pragma unroll
      for (int rg = 0; rg < 4; ++rg) {
        ovA[rg] = (bf16_t)((o[dt][0][rg] + pA[rg]) * invA);
        ovB[rg] = (bf16_t)((o[dt][1][rg] + pB[rg]) * invB);
      }
      *(bf16x4*)(outp + (size_t)qrA * DMODEL + h * DKH + dt * 16 + quad * 4) = ovA;
      *(bf16x4*)(outp + (size_t)qrB * DMODEL + h * DKH + dt * 16 + quad * 4) = ovB;
    }
  }
}

extern "C" void kernel_launch(void* const* d_in, const int* in_sizes, int n_in,
                              void* d_out, int out_size, void* d_ws, size_t ws_size,
                              hipStream_t stream) {
  const float* q  = (const float*)d_in[0];
  const float* k  = (const float*)d_in[1];
  const float* v  = (const float*)d_in[2];
  const float* Wq = (const float*)d_in[3];
  const float* bq = (const float*)d_in[4];
  const float* Wk = (const float*)d_in[5];
  const float* bk = (const float*)d_in[6];
  const float* Wv = (const float*)d_in[7];
  const float* bv = (const float*)d_in[8];
  const float* Wo = (const float*)d_in[9];
  const float* bo = (const float*)d_in[10];
  float* out = (float*)d_out;
  char* ws = (char*)d_ws;

  const size_t MB = 1u << 20;
  bf16_t* Wqt = (bf16_t*)(ws);                   // 2 MB
  bf16_t* Wot = (bf16_t*)(ws + 2 * MB);          // 2 MB
  bf16_t* Wkt = (bf16_t*)(ws + 4 * MB);          // 128 KB [64][1024]
  bf16_t* Wvt = (bf16_t*)(ws + 4 * MB + 131072); // 128 KB
  bf16_t* kvb = (bf16_t*)(ws + 4 * MB + 524288); // 1 MB [4096][128] (K | V)
  bf16_t* vtb = (bf16_t*)(ws + 5 * MB + 524288); // 512 KB [64][4096]

  const bool bigws = ws_size >= (size_t)30 * MB;
  dim3 B(256);
  const float LOG2E = 1.44269504088896340736f;

  if (bigws) {
    // Layout: qp@14 (8 MB), qb@22 (8 MB), attn@6 (8 MB). No Pk/Pv (direct K/V proj).
    bf16_t* qp   = (bf16_t*)(ws + 14 * MB);
    bf16_t* qb   = (bf16_t*)(ws + 22 * MB);
    bf16_t* attn = (bf16_t*)(ws + 6 * MB);

    prep_weights<<<dim3(2592), B, 0, stream>>>(Wq, Wo, Wk, Wv, q, Wqt, Wot, Wkt, Wvt, qb);
    // fused: K/V direct projection (blocks 0..127) + Q-projection (128..639)
    mid_gemms<<<dim3(640), B, 0, stream>>>(qb, Wqt, bq, qp, k, v, Wkt, Wvt, bk, bv,
                                           kvb, vtb, LOG2E);
    mqa_attn<<<dim3(32, 16), dim3(512), 0, stream>>>(qp, kvb, vtb, attn);
    gemm_nt_dma<float><<<dim3(16, 32), B, 0, stream>>>(attn, 1024, Wot, 1024, bo, out,
                                                       1024, 1024, 1.0f);
  } else {
    // Fallback: round-12 small-workspace path (KSPLIT=8, separate dispatches).
    float*  Pk   = (float*)(ws + 6 * MB);
    float*  Pv   = (float*)(ws + 14 * MB);
    bf16_t* qp   = (bf16_t*)(ws + 14 * MB);
    bf16_t* qb   = (bf16_t*)(ws + 6 * MB);
    bf16_t* attn = (bf16_t*)(ws + 6 * MB);

    prep_weights<<<dim3(544), B, 0, stream>>>(Wq, Wo, Wk, Wv, q, Wqt, Wot, Wkt, Wvt, qb);
    gemm_projkv_partial<8><<<dim3(8, 32, 2), B, 0, stream>>>(k, v, Wkt, Wvt, Pk, Pv);
    reduce_kv<8><<<dim3(128), dim3(512), 0, stream>>>(Pk, Pv, bk, bv, kvb, vtb);
    convert_bf16<<<dim3(2048), B, 0, stream>>>(q, qb);  // overwrites Pk (consumed)
    gemm_nt_dma<bf16_t><<<dim3(16, 32), B, 0, stream>>>(qb, 1024, Wqt, 1024, bq, qp,
                                                        1024, 1024, LOG2E);
    mqa_attn<<<dim3(32, 16), dim3(512), 0, stream>>>(qp, kvb, vtb, attn);
    gemm_nt_dma<float><<<dim3(16, 32), B, 0, stream>>>(attn, 1024, Wot, 1024, bo, out,
                                                       1024, 1024, 1.0f);
  }
}

// Round 15
// 229.821 us; speedup vs baseline: 1.0405x; 1.0405x over previous
//
#include <hip/hip_runtime.h>
#include <hip/hip_bf16.h>
#include <stdint.h>

typedef __bf16 bf16_t;
typedef __attribute__((ext_vector_type(8))) __bf16 bf16x8;
typedef __attribute__((ext_vector_type(4))) __bf16 bf16x4;
typedef __attribute__((ext_vector_type(4))) float f32x4;

#define S_LEN 4096
#define DMODEL 1024
#define NHEADS 16
#define DKH 64

// Hardware 2^x (v_exp_f32). Fallback is numerically identical (e^(x ln2)).
#if defined(__has_builtin)
#if __has_builtin(__builtin_amdgcn_exp2f)
#define EXP2F(x) __builtin_amdgcn_exp2f(x)
#endif
#endif
#ifndef EXP2F
#define EXP2F(x) __expf((x)*0.6931471805599453f)
#endif

__device__ __forceinline__ f32x4 mfma16(bf16x8 a, bf16x8 b, f32x4 c) {
  return __builtin_amdgcn_mfma_f32_16x16x32_bf16(a, b, c, 0, 0, 0);
}

// Load 8 consecutive elements at g (fp32 or bf16) as bf16x8.
template <typename TS>
__device__ __forceinline__ bf16x8 load8_bf16(const TS* g) {
  bf16x8 o;
  if constexpr (sizeof(TS) == 4) {
    const float4 f0 = *(const float4*)(g);
    const float4 f1 = *(const float4*)(g + 4);
    o[0] = (bf16_t)f0.x; o[1] = (bf16_t)f0.y; o[2] = (bf16_t)f0.z; o[3] = (bf16_t)f0.w;
    o[4] = (bf16_t)f1.x; o[5] = (bf16_t)f1.y; o[6] = (bf16_t)f1.z; o[7] = (bf16_t)f1.w;
  } else {
    o = *(const bf16x8*)(g);
  }
  return o;
}

// Sync staging: LDS[row][c] holds global chunk c^(row&7) (chunk = 8 elem = 16 B).
// Lane j loads global chunk j (coalesced) and writes physical chunk j^(row&7).
template <typename TS>
__device__ __forceinline__ void stage_tile64(const TS* __restrict__ g, int gstride,
                                             bf16_t* lds, int rows, int tid) {
  for (int i = tid; i < rows * 8; i += 256) {
    const int row = i >> 3, j = i & 7;
    const int c = j ^ (row & 7);
    bf16x8 v = load8_bf16(g + (size_t)row * gstride + j * 8);
    *(bf16x8*)((char*)lds + row * 128 + c * 16) = v;
  }
}

__device__ __forceinline__ bf16x8 frag64(const bf16_t* lds, int row, int g) {
  return *(const bf16x8*)((const char*)lds + row * 128 + ((g ^ (row & 7)) * 16));
}

// async 16B global->LDS DMA (dest = wave-uniform base + lane*16)
__device__ __forceinline__ void gload16(const bf16_t* g, bf16_t* lds) {
  __builtin_amdgcn_global_load_lds(
      (const __attribute__((address_space(1))) unsigned int*)g,
      (__attribute__((address_space(3))) unsigned int*)lds, 16, 0, 0);
}

// ---------------- elementwise fp32 -> bf16 (fallback path only) ----------------
__global__ __launch_bounds__(256) void convert_bf16(const float* __restrict__ src,
                                                    bf16_t* __restrict__ dst) {
  const size_t i = (size_t)(blockIdx.x * 256 + threadIdx.x) * 8;
  bf16x8 v = load8_bf16(src + i);
  *(bf16x8*)(dst + i) = v;
}

// ---------------- merged head: weight transposes (+ optional q conversion) ----------------
__global__ __launch_bounds__(256) void prep_weights(const float* __restrict__ Wq,
                                                    const float* __restrict__ Wo,
                                                    const float* __restrict__ Wk,
                                                    const float* __restrict__ Wv,
                                                    const float* __restrict__ qsrc,
                                                    bf16_t* __restrict__ Wqt,
                                                    bf16_t* __restrict__ Wot,
                                                    bf16_t* __restrict__ Wkt,
                                                    bf16_t* __restrict__ Wvt,
                                                    bf16_t* __restrict__ qdst) {
  const int b = blockIdx.x;
  const int tid = threadIdx.x;
  if (b >= 544) {  // q conversion chunk
    const size_t i = ((size_t)(b - 544) * 256 + tid) * 8;
    bf16x8 v = load8_bf16(qsrc + i);
    *(bf16x8*)(qdst + i) = v;
    return;
  }
  const float* src; bf16_t* dst; int ss, ds_, bx, by;
  if (b < 256)      { src = Wq; dst = Wqt; ss = 1024; ds_ = 1024; bx = b & 15;         by = b >> 4; }
  else if (b < 512) { src = Wo; dst = Wot; ss = 1024; ds_ = 1024; bx = (b - 256) & 15; by = (b - 256) >> 4; }
  else if (b < 528) { src = Wk; dst = Wkt; ss = 64;   ds_ = 1024; bx = 0;              by = b - 512; }
  else              { src = Wv; dst = Wvt; ss = 64;   ds_ = 1024; bx = 0;              by = b - 528; }

  __shared__ bf16_t t[64][65];
  const int r0 = by * 64, c0 = bx * 64;
#pragma unroll
  for (int it = 0; it < 2; ++it) {
    int idx = tid + it * 256;
    int r = idx >> 3, c8 = idx & 7;
    bf16x8 v = load8_bf16(src + (size_t)(r0 + r) * ss + c0 + c8 * 8);
#pragma unroll
    for (int j = 0; j < 8; ++j) t[c8 * 8 + j][r] = v[j];
  }
  __syncthreads();
#pragma unroll
  for (int it = 0; it < 2; ++it) {
    int idx = tid + it * 256;
    int r = idx >> 3, c8 = idx & 7;
    bf16x8 v;
#pragma unroll
    for (int j = 0; j < 8; ++j) v[j] = t[r][c8 * 8 + j];
    *(bf16x8*)(dst + (size_t)(c0 + r) * ds_ + r0 + c8 * 8) = v;
  }
}

// ---------------- DMA NT GEMM device body (shared by standalone + fused kernels) ----------------
template <typename TC>
__device__ __forceinline__ void gemm_body_dma(char* smem,
                                              const bf16_t* __restrict__ A, int lda,
                                              const bf16_t* __restrict__ Bt, int ldb,
                                              const float* __restrict__ bias,
                                              TC* __restrict__ C, int ldc, int K,
                                              float escale, int m0, int n0) {
  constexpr int BM = 128, BN = 64;
  bf16_t* As = (bf16_t*)smem;            // 2 x 16 KB
  bf16_t* Bs = (bf16_t*)(smem + 32768);  // 2 x 8 KB
  const int tid = threadIdx.x, l = tid & 63, w = tid >> 6;
  const int lr = l & 15, quad = l >> 4;
  const int wm = w * 32;

  const int srow = l >> 3;
  const int sch = (l & 7) ^ srow;
  const bf16_t* a0 = A + (size_t)(m0 + w * 32 + srow) * lda + sch * 8;  // 4 sub-blocks of 8 rows
  const bf16_t* b0 = Bt + (size_t)(n0 + w * 16 + srow) * ldb + sch * 8; // 2 sub-blocks of 8 rows

  f32x4 zero = {0.f, 0.f, 0.f, 0.f};
  f32x4 acc[2][4];
#pragma unroll
  for (int i = 0; i < 2; ++i)
#pragma unroll
    for (int j = 0; j < 4; ++j) acc[i][j] = zero;

  const int nt = K >> 6;

#pragma unroll
  for (int sub = 0; sub < 4; ++sub)
    gload16(a0 + (size_t)sub * 8 * lda, &As[(w * 32 + sub * 8) * 64]);
#pragma unroll
  for (int sub = 0; sub < 2; ++sub)
    gload16(b0 + (size_t)sub * 8 * ldb, &Bs[(w * 16 + sub * 8) * 64]);
  asm volatile("s_waitcnt vmcnt(0)" ::: "memory");
  __builtin_amdgcn_s_barrier();
  asm volatile("" ::: "memory");

  for (int t = 0; t < nt; ++t) {
    const int cur = t & 1;
    if (t + 1 < nt) {
#pragma unroll
      for (int sub = 0; sub < 4; ++sub)
        gload16(a0 + (size_t)(t + 1) * 64 + (size_t)sub * 8 * lda,
                &As[(cur ^ 1) * BM * 64 + (w * 32 + sub * 8) * 64]);
#pragma unroll
      for (int sub = 0; sub < 2; ++sub)
        gload16(b0 + (size_t)(t + 1) * 64 + (size_t)sub * 8 * ldb,
                &Bs[(cur ^ 1) * BN * 64 + (w * 16 + sub * 8) * 64]);
    }
    const bf16_t* Ac = &As[cur * BM * 64];
    const bf16_t* Bc = &Bs[cur * BN * 64];
#pragma unroll
    for (int kc = 0; kc < 2; ++kc) {
      bf16x8 af[2], bfr[4];
#pragma unroll
      for (int rt = 0; rt < 2; ++rt) af[rt] = frag64(Ac, wm + rt * 16 + lr, kc * 4 + quad);
#pragma unroll
      for (int ct = 0; ct < 4; ++ct) bfr[ct] = frag64(Bc, ct * 16 + lr, kc * 4 + quad);
#pragma unroll
      for (int rt = 0; rt < 2; ++rt)
#pragma unroll
        for (int ct = 0; ct < 4; ++ct) acc[rt][ct] = mfma16(af[rt], bfr[ct], acc[rt][ct]);
    }
    asm volatile("s_waitcnt vmcnt(0) lgkmcnt(0)" ::: "memory");
    __builtin_amdgcn_s_barrier();
    asm volatile("" ::: "memory");
  }

#pragma unroll
  for (int rt = 0; rt < 2; ++rt)
#pragma unroll
    for (int ct = 0; ct < 4; ++ct) {
      const int n = n0 + ct * 16 + lr;
      const float bv = bias[n];
      const int mb = m0 + wm + rt * 16 + quad * 4;
#pragma unroll
      for (int r = 0; r < 4; ++r)
        C[(size_t)(mb + r) * ldc + n] = (TC)((acc[rt][ct][r] + bv) * escale);
    }
}

template <typename TC>
__global__ __launch_bounds__(256) void gemm_nt_dma(const bf16_t* __restrict__ A, int lda,
                                                   const bf16_t* __restrict__ Bt, int ldb,
                                                   const float* __restrict__ bias,
                                                   TC* __restrict__ C, int ldc, int K,
                                                   float escale) {
  __shared__ __align__(16) char smem[49152];
  gemm_body_dma<TC>(smem, A, lda, Bt, ldb, bias, C, ldc, K, escale,
                    blockIdx.y * 128, blockIdx.x * 64);
}

// ---------------- K+V split-K projection body ----------------
template <int KSPLIT>
__device__ __forceinline__ void projkv_body(char* smem,
                                            const float* __restrict__ A,
                                            const bf16_t* __restrict__ Bt,
                                            float* __restrict__ part,
                                            int kp, int m0) {
  bf16_t* As = (bf16_t*)smem;            // 16 KB
  bf16_t* Bs = (bf16_t*)(smem + 16384);  // 8 KB
  const int tid = threadIdx.x, l = tid & 63, w = tid >> 6;
  const int lr = l & 15, quad = l >> 4;
  const int kBase = kp * (DMODEL / KSPLIT);
  const int wm = w * 32;

  f32x4 zero = {0.f, 0.f, 0.f, 0.f};
  f32x4 acc[2][4];
#pragma unroll
  for (int i = 0; i < 2; ++i)
#pragma unroll
    for (int j = 0; j < 4; ++j) acc[i][j] = zero;

  for (int t = 0; t < (DMODEL / KSPLIT) / 64; ++t) {
    __syncthreads();
    stage_tile64(A + (size_t)m0 * DMODEL + kBase + t * 64, DMODEL, As, 128, tid);
    stage_tile64(Bt + kBase + t * 64, DMODEL, Bs, 64, tid);
    __syncthreads();
#pragma unroll
    for (int kc = 0; kc < 2; ++kc) {
      bf16x8 af[2], bfr[4];
#pragma unroll
      for (int rt = 0; rt < 2; ++rt) af[rt] = frag64(As, wm + rt * 16 + lr, kc * 4 + quad);
#pragma unroll
      for (int ct = 0; ct < 4; ++ct) bfr[ct] = frag64(Bs, ct * 16 + lr, kc * 4 + quad);
#pragma unroll
      for (int rt = 0; rt < 2; ++rt)
#pragma unroll
        for (int ct = 0; ct < 4; ++ct) acc[rt][ct] = mfma16(af[rt], bfr[ct], acc[rt][ct]);
    }
  }
#pragma unroll
  for (int rt = 0; rt < 2; ++rt)
#pragma unroll
    for (int ct = 0; ct < 4; ++ct) {
      const int n = ct * 16 + lr;
      const int mb = m0 + wm + rt * 16 + quad * 4;
#pragma unroll
      for (int r = 0; r < 4; ++r)
        part[(size_t)kp * S_LEN * 64 + (size_t)(mb + r) * 64 + n] = acc[rt][ct][r];
    }
}

template <int KSPLIT>
__global__ __launch_bounds__(256) void gemm_projkv_partial(const float* __restrict__ Ak,
                                                           const float* __restrict__ Av,
                                                           const bf16_t* __restrict__ Wkt,
                                                           const bf16_t* __restrict__ Wvt,
                                                           float* __restrict__ Pk,
                                                           float* __restrict__ Pv) {
  __shared__ __align__(16) char smem[24576];
  projkv_body<KSPLIT>(smem, blockIdx.z ? Av : Ak, blockIdx.z ? Wvt : Wkt,
                      blockIdx.z ? Pv : Pk, blockIdx.x, blockIdx.y * 128);
}

// ---------------- fused mid dispatch: Q-proj (512 blocks) + K/V-proj (256 blocks, KSPLIT=4) ----
__global__ __launch_bounds__(256) void mid_gemms(const bf16_t* __restrict__ qb,
                                                 const bf16_t* __restrict__ Wqt,
                                                 const float* __restrict__ bq,
                                                 bf16_t* __restrict__ qp,
                                                 const float* __restrict__ k,
                                                 const float* __restrict__ v,
                                                 const bf16_t* __restrict__ Wkt,
                                                 const bf16_t* __restrict__ Wvt,
                                                 float* __restrict__ Pk,
                                                 float* __restrict__ Pv,
                                                 float escale) {
  __shared__ __align__(16) char smem[49152];
  const int flat = blockIdx.x;
  if (flat < 512) {
    gemm_body_dma<bf16_t>(smem, qb, 1024, Wqt, 1024, bq, qp, 1024, 1024, escale,
                          (flat >> 4) * 128, (flat & 15) * 64);
  } else {
    const int j = flat - 512;       // 0..255
    const int z = j >> 7;           // 0 = K, 1 = V
    const int jj = j & 127;         // 4 kp x 32 m-blocks
    projkv_body<4>(smem, z ? v : k, z ? Wvt : Wkt, z ? Pv : Pk, jj & 3, (jj >> 2) * 128);
  }
}

// ---------------- reduce split-K partials: coalesced vtb via LDS transpose ----------------
template <int KSPLIT>
__global__ __launch_bounds__(512) void reduce_kv(const float* __restrict__ Pk,
                                                 const float* __restrict__ Pv,
                                                 const float* __restrict__ bk,
                                                 const float* __restrict__ bv,
                                                 bf16_t* __restrict__ kvb,
                                                 bf16_t* __restrict__ vtb) {
  __shared__ bf16_t t[32][65];
  const int tid = threadIdx.x;
  const int s0 = blockIdx.x * 32;
  const int d = tid & 63;
  const int sgrp = tid >> 6;  // 0..7
  const float bkd = bk[d], bvd = bv[d];
#pragma unroll
  for (int i = 0; i < 4; ++i) {
    const int s_local = sgrp * 4 + i;  // 0..31
    const int gid = (s0 + s_local) * 64 + d;
    float sk = bkd, sv = bvd;
#pragma unroll
    for (int p = 0; p < KSPLIT; ++p) {
      sk += Pk[(size_t)p * S_LEN * 64 + gid];
      sv += Pv[(size_t)p * S_LEN * 64 + gid];
    }
    kvb[(size_t)(s0 + s_local) * 128 + d] = (bf16_t)sk;
    kvb[(size_t)(s0 + s_local) * 128 + 64 + d] = (bf16_t)sv;
    t[s_local][d] = (bf16_t)sv;
  }
  __syncthreads();
  if (tid < 256) {
    const int dl = tid >> 2;   // 0..63
    const int s8 = tid & 3;    // chunk of 8 s
    bf16x8 v;
#pragma unroll
    for (int j = 0; j < 8; ++j) v[j] = t[s8 * 8 + j][dl];
    *(bf16x8*)(vtb + (size_t)dl * S_LEN + s0 + s8 * 8) = v;
  }
}

// ---------------- fused flash-style MQA attention v12 (verified best) ----------------
__global__ __launch_bounds__(512, 4) void mqa_attn(const bf16_t* __restrict__ qp,
                                                   const bf16_t* __restrict__ kvb,
                                                   const bf16_t* __restrict__ vtb,
                                                   bf16_t* __restrict__ outp) {
  __shared__ __align__(16) char smem[49152];        // 48 KB
  bf16_t* Ks = (bf16_t*)smem;                       // [2][4096] bf16, 16 KB
  bf16_t* Vs = (bf16_t*)(smem + 16384);             // [2][4096] bf16, 16 KB
  char*   Ps = smem + 32768;                        // 8 waves x 2 KB

  const int tid = threadIdx.x, l = tid & 63, w = tid >> 6;
  const int lr = l & 15, quad = l >> 4;
  const int wq = w >> 1, wk = w & 1;
  const int h = blockIdx.y;
  const int q0 = blockIdx.x * 128;
  const int qrA = q0 + wq * 32 + lr;  // q-tile 0 rows
  const int qrB = qrA + 16;           // q-tile 1 rows
  char* Pw = Ps + w * 2048;           // wave-private [16 rows][128 B]

  const int srow = w * 8 + (l >> 3);
  const int schunk = (l & 7) ^ (srow & 7);
  const bf16_t* ksrc = kvb + (size_t)srow * 128 + schunk * 8;    // +8192 elems/tile
  const bf16_t* vsrc = vtb + (size_t)srow * S_LEN + schunk * 8;  // +64 elems/tile

  const bf16_t* qbA = qp + (size_t)qrA * DMODEL + h * DKH;
  const bf16x8 qfA0 = *(const bf16x8*)(qbA + quad * 8);
  const bf16x8 qfA1 = *(const bf16x8*)(qbA + 32 + quad * 8);
  const bf16_t* qbB = qp + (size_t)qrB * DMODEL + h * DKH;
  const bf16x8 qfB0 = *(const bf16x8*)(qbB + quad * 8);
  const bf16x8 qfB1 = *(const bf16x8*)(qbB + 32 + quad * 8);

  f32x4 zero = {0.f, 0.f, 0.f, 0.f};
  f32x4 o[4][2];  // [d-tile][q-tile], partial over this wave's keys
#pragma unroll
  for (int dt = 0; dt < 4; ++dt) { o[dt][0] = zero; o[dt][1] = zero; }
  float liA = 0.f, liB = 0.f;

  gload16(ksrc, Ks + w * 512);
  gload16(vsrc, Vs + w * 512);
  asm volatile("s_waitcnt vmcnt(0)" ::: "memory");
  __builtin_amdgcn_s_barrier();
  asm volatile("" ::: "memory");

  for (int t = 0; t < S_LEN / 64; ++t) {
    const int cur = t & 1;
    if (t + 1 < S_LEN / 64) {
      gload16(ksrc + (size_t)(t + 1) * 8192, Ks + (cur ^ 1) * 4096 + w * 512);
      gload16(vsrc + (size_t)(t + 1) * 64, Vs + (cur ^ 1) * 4096 + w * 512);
    }
    const bf16_t* Kc = Ks + cur * 4096;
    const bf16_t* Vc = Vs + cur * 4096;

    // ---- S^T = K·Q^T on this wave's 32-key half, both q-tiles ----
    f32x4 st[2][2];  // [kt][qt]
#pragma unroll
    for (int kt = 0; kt < 2; ++kt) {
      const int krow = wk * 32 + kt * 16 + lr;
      const bf16x8 kf0 = frag64(Kc, krow, quad);
      const bf16x8 kf1 = frag64(Kc, krow, 4 + quad);
      f32x4 a0 = mfma16(kf0, qfA0, zero);
      a0 = mfma16(kf1, qfA1, a0);
      st[kt][0] = a0;
      f32x4 a1 = mfma16(kf0, qfB0, zero);
      a1 = mfma16(kf1, qfB1, a1);
      st[kt][1] = a1;
    }

    // ---- p = 2^(s') (Q pre-scaled by log2e); li; pack P (128-B rows) ----
#pragma unroll
    for (int kt = 0; kt < 2; ++kt)
#pragma unroll
      for (int qt = 0; qt < 2; ++qt) {
        bf16x4 pk;
        float rs = 0.f;
#pragma unroll
        for (int r = 0; r < 4; ++r) {
          const float p = EXP2F(st[kt][qt][r]);
          rs += p;
          pk[r] = (bf16_t)p;
        }
        if (qt == 0) liA += rs; else liB += rs;
        *(bf16x4*)(Pw + lr * 128 +
                   ((((qt << 2) + (kt << 1) + (quad >> 1)) ^ (lr & 7)) << 4) +
                   ((quad & 1) << 3)) = pk;
      }
    asm volatile("s_waitcnt lgkmcnt(0)" ::: "memory");  // wave-local drain; no barrier

    // ---- O^T += V^T·P^T on this wave's keys: vf read once, both q-tiles ----
    const bf16x8 pf0 = *(const bf16x8*)(Pw + lr * 128 + ((quad ^ (lr & 7)) << 4));
    const bf16x8 pf1 = *(const bf16x8*)(Pw + lr * 128 + (((4 + quad) ^ (lr & 7)) << 4));
#pragma unroll
    for (int dt = 0; dt < 4; ++dt) {
      const bf16x8 vf = frag64(Vc, dt * 16 + lr, wk * 4 + quad);
      o[dt][0] = mfma16(vf, pf0, o[dt][0]);
      o[dt][1] = mfma16(vf, pf1, o[dt][1]);
    }

    asm volatile("s_waitcnt vmcnt(0) lgkmcnt(0)" ::: "memory");
    __builtin_amdgcn_s_barrier();
    asm volatile("" ::: "memory");
  }

  // ---- epilogue: reduce li over quads in-wave, then pair-sum (wk) via LDS ----
  liA += __shfl_xor(liA, 16, 64);
  liA += __shfl_xor(liA, 32, 64);
  liB += __shfl_xor(liB, 16, 64);
  liB += __shfl_xor(liB, 32, 64);

  float* liBuf = (float*)Ps;  // Ps dead (own-wave pf reads done pre-barrier)
  if (quad == 0) {
    liBuf[w * 32 + lr] = liA;
    liBuf[w * 32 + 16 + lr] = liB;
  }
  float* Obuf = (float*)smem;  // 32 KB: [wq][32 q][64 d]
  if (wk == 1) {
#pragma unroll
    for (int dt = 0; dt < 4; ++dt)
#pragma unroll
      for (int qt = 0; qt < 2; ++qt)
        *(f32x4*)(&Obuf[wq * 2048 + (qt * 16 + lr) * 64 + dt * 16 + quad * 4]) = o[dt][qt];
  }
  __syncthreads();
  if (wk == 0) {
    const float ltA = liA + liBuf[(w ^ 1) * 32 + lr];
    const float ltB = liB + liBuf[(w ^ 1) * 32 + 16 + lr];
    const float invA = 1.f / ltA;
    const float invB = 1.f / ltB;
#pragma unroll
    for (int dt = 0; dt < 4; ++dt) {
      const f32x4 pA = *(const f32x4*)(&Obuf[wq * 2048 + lr * 64 + dt * 16 + quad * 4]);
      const f32x4 pB = *(const f32x4*)(&Obuf[wq * 2048 + (16 + lr) * 64 + dt * 16 + quad * 4]);
      bf16x4 ovA, ovB;
#pragma unroll
      for (int rg = 0; rg < 4; ++rg) {
        ovA[rg] = (bf16_t)((o[dt][0][rg] + pA[rg]) * invA);
        ovB[rg] = (bf16_t)((o[dt][1][rg] + pB[rg]) * invB);
      }
      *(bf16x4*)(outp + (size_t)qrA * DMODEL + h * DKH + dt * 16 + quad * 4) = ovA;
      *(bf16x4*)(outp + (size_t)qrB * DMODEL + h * DKH + dt * 16 + quad * 4) = ovB;
    }
  }
}

extern "C" void kernel_launch(void* const* d_in, const int* in_sizes, int n_in,
                              void* d_out, int out_size, void* d_ws, size_t ws_size,
                              hipStream_t stream) {
  const float* q  = (const float*)d_in[0];
  const float* k  = (const float*)d_in[1];
  const float* v  = (const float*)d_in[2];
  const float* Wq = (const float*)d_in[3];
  const float* bq = (const float*)d_in[4];
  const float* Wk = (const float*)d_in[5];
  const float* bk = (const float*)d_in[6];
  const float* Wv = (const float*)d_in[7];
  const float* bv = (const float*)d_in[8];
  const float* Wo = (const float*)d_in[9];
  const float* bo = (const float*)d_in[10];
  float* out = (float*)d_out;
  char* ws = (char*)d_ws;

  const size_t MB = 1u << 20;
  bf16_t* Wqt = (bf16_t*)(ws);                   // 2 MB
  bf16_t* Wot = (bf16_t*)(ws + 2 * MB);          // 2 MB
  bf16_t* Wkt = (bf16_t*)(ws + 4 * MB);          // 128 KB [64][1024]
  bf16_t* Wvt = (bf16_t*)(ws + 4 * MB + 131072); // 128 KB
  bf16_t* kvb = (bf16_t*)(ws + 4 * MB + 524288); // 1 MB [4096][128] (K | V)
  bf16_t* vtb = (bf16_t*)(ws + 5 * MB + 524288); // 512 KB [64][4096]

  const bool bigws = ws_size >= (size_t)30 * MB;
  dim3 B(256);
  const float LOG2E = 1.44269504088896340736f;

  if (bigws) {
    // Layout: Pk@6 (4 MB, KSPLIT=4), Pv@10 (4 MB), qp@14 (8 MB), qb@22 (8 MB),
    //         attn@6 (overwrites Pk+Pv after reduce consumed them).
    float*  Pk   = (float*)(ws + 6 * MB);
    float*  Pv   = (float*)(ws + 10 * MB);
    bf16_t* qp   = (bf16_t*)(ws + 14 * MB);
    bf16_t* qb   = (bf16_t*)(ws + 22 * MB);
    bf16_t* attn = (bf16_t*)(ws + 6 * MB);

    prep_weights<<<dim3(2592), B, 0, stream>>>(Wq, Wo, Wk, Wv, q, Wqt, Wot, Wkt, Wvt, qb);
    // fused: Q-projection (blocks 0..511) + K/V split-K=4 partials (512..767)
    mid_gemms<<<dim3(768), B, 0, stream>>>(qb, Wqt, bq, qp, k, v, Wkt, Wvt, Pk, Pv, LOG2E);
    reduce_kv<4><<<dim3(128), dim3(512), 0, stream>>>(Pk, Pv, bk, bv, kvb, vtb);
    mqa_attn<<<dim3(32, 16), dim3(512), 0, stream>>>(qp, kvb, vtb, attn);
    gemm_nt_dma<float><<<dim3(16, 32), B, 0, stream>>>(attn, 1024, Wot, 1024, bo, out,
                                                       1024, 1024, 1.0f);
  } else {
    // Fallback: round-12 small-workspace path (KSPLIT=8, separate dispatches).
    float*  Pk   = (float*)(ws + 6 * MB);
    float*  Pv   = (float*)(ws + 14 * MB);
    bf16_t* qp   = (bf16_t*)(ws + 14 * MB);
    bf16_t* qb   = (bf16_t*)(ws + 6 * MB);
    bf16_t* attn = (bf16_t*)(ws + 6 * MB);

    prep_weights<<<dim3(544), B, 0, stream>>>(Wq, Wo, Wk, Wv, q, Wqt, Wot, Wkt, Wvt, qb);
    gemm_projkv_partial<8><<<dim3(8, 32, 2), B, 0, stream>>>(k, v, Wkt, Wvt, Pk, Pv);
    reduce_kv<8><<<dim3(128), dim3(512), 0, stream>>>(Pk, Pv, bk, bv, kvb, vtb);
    convert_bf16<<<dim3(2048), B, 0, stream>>>(q, qb);  // overwrites Pk (consumed)
    gemm_nt_dma<bf16_t><<<dim3(16, 32), B, 0, stream>>>(qb, 1024, Wqt, 1024, bq, qp,
                                                        1024, 1024, LOG2E);
    mqa_attn<<<dim3(32, 16), dim3(512), 0, stream>>>(qp, kvb, vtb, attn);
    gemm_nt_dma<float><<<dim3(16, 32), B, 0, stream>>>(attn, 1024, Wot, 1024, bo, out,
                                                       1024, 1024, 1.0f);
  }
}